// Round 13
// baseline (119.871 us; speedup 1.0000x reference)
//
#include <hip/hip_runtime.h>
#include <stdint.h>

// fp32 inputs, fp32 outputs (established R8):
// qps/kps: [256][32][8][64] f32 ; qpn/kpn: [256][8][8][64] f32
// d_out: f32, FIRST s_ps repeat-expanded [8][8][256][256] (4,194,304 elems),
// THEN s_pn tiled [8][8][256][256].
// S[b,h,l,s] = (1/8)*sum_e Q[b,l,h,e]K[b,s,h,e]; softmax over s; mean over
// the 32 channels (b = bo*32+ch).
//
// R13: scores branch-A K-loop double-buffered (prefetch c+1 during FMA c),
// __launch_bounds__(256,4) to allow ~128 VGPR (R12 was 64 VGPR -> serialized
// 16 load batches at L2/L3 latency each). Reduce + writer = R12 verbatim.

__global__ __launch_bounds__(256, 4)
void scores_kernel(const float* __restrict__ qps,
                   const float* __restrict__ kps,
                   const float* __restrict__ qpn,
                   const float* __restrict__ kpn,
                   float* __restrict__ ws_ps,   // [64][8][1024] chunk partials
                   float* __restrict__ ws_pn)   // [64][8][64]   chunk partials
{
    __shared__ float red[4][32 * 36];   // per-wave 32 rows (l) x 36 (s, +4 pad)
    const int tid  = threadIdx.x;
    const int wv   = tid >> 6;
    const int lane = tid & 63;
    const int blk  = blockIdx.x;

    if (blk < 512) {
        // ---- patch_size: one wave = one (a, ch) 32x32 softmax ----
        const int a     = blk >> 3;    // bo*8 + h
        const int chunk = blk & 7;
        const int bo = a >> 3, h = a & 7;
        const int ch = chunk * 4 + wv;
        const int b  = bo * 32 + ch;
        const int i = lane >> 3, j = lane & 7;   // lane owns l=4i..4i+3, s=4j..4j+3

        const float4* Q = reinterpret_cast<const float4*>(qps) + ((b * 32 + 4 * i) * 8 + h) * 16;
        const float4* K = reinterpret_cast<const float4*>(kps) + ((b * 32 + 4 * j) * 8 + h) * 16;

        float acc[4][4];
        #pragma unroll
        for (int r = 0; r < 4; ++r)
            #pragma unroll
            for (int c = 0; c < 4; ++c) acc[r][c] = 0.f;

        // Double-buffered K-loop: batch = 8 float4 loads (4 Q-rows + 4 K-rows).
        float4 q0[4], k0[4], q1[4], k1[4];
        #pragma unroll
        for (int r = 0; r < 4; ++r) { q0[r] = Q[r * 128]; k0[r] = K[r * 128]; }

        #pragma unroll
        for (int c = 0; c < 16; ++c) {   // e-chunks of 4; row stride = 128 float4
            if (c < 15) {
                #pragma unroll
                for (int r = 0; r < 4; ++r) {
                    q1[r] = Q[r * 128 + c + 1];
                    k1[r] = K[r * 128 + c + 1];
                }
            }
            #pragma unroll
            for (int r = 0; r < 4; ++r)
                #pragma unroll
                for (int u = 0; u < 4; ++u) {
                    acc[r][u] = fmaf(q0[r].x, k0[u].x, acc[r][u]);
                    acc[r][u] = fmaf(q0[r].y, k0[u].y, acc[r][u]);
                    acc[r][u] = fmaf(q0[r].z, k0[u].z, acc[r][u]);
                    acc[r][u] = fmaf(q0[r].w, k0[u].w, acc[r][u]);
                }
            if (c < 15) {
                #pragma unroll
                for (int r = 0; r < 4; ++r) { q0[r] = q1[r]; k0[r] = k1[r]; }
            }
        }

        // softmax over s (own 4 + shfl across j bits 1,2,4); fold 1/32 mean
        #pragma unroll
        for (int r = 0; r < 4; ++r) {
            float v0 = acc[r][0] * 0.125f, v1 = acc[r][1] * 0.125f;
            float v2 = acc[r][2] * 0.125f, v3 = acc[r][3] * 0.125f;
            float m = fmaxf(fmaxf(v0, v1), fmaxf(v2, v3));
            m = fmaxf(m, __shfl_xor(m, 1));
            m = fmaxf(m, __shfl_xor(m, 2));
            m = fmaxf(m, __shfl_xor(m, 4));
            float e0 = __expf(v0 - m), e1 = __expf(v1 - m);
            float e2 = __expf(v2 - m), e3 = __expf(v3 - m);
            float s = (e0 + e1) + (e2 + e3);
            s += __shfl_xor(s, 1);
            s += __shfl_xor(s, 2);
            s += __shfl_xor(s, 4);
            const float inv = 1.f / (s * 32.f);
            float4 p; p.x = e0 * inv; p.y = e1 * inv; p.z = e2 * inv; p.w = e3 * inv;
            *reinterpret_cast<float4*>(&red[wv][(4 * i + r) * 36 + 4 * j]) = p;
        }
        __syncthreads();

        // cross-wave reduce (4 channels) -> plain float4 store of the partial
        const int l = tid >> 3, s4 = (tid & 7) * 4;
        const float4 u0 = *reinterpret_cast<const float4*>(&red[0][l * 36 + s4]);
        const float4 u1 = *reinterpret_cast<const float4*>(&red[1][l * 36 + s4]);
        const float4 u2 = *reinterpret_cast<const float4*>(&red[2][l * 36 + s4]);
        const float4 u3 = *reinterpret_cast<const float4*>(&red[3][l * 36 + s4]);
        float4 o;
        o.x = (u0.x + u1.x) + (u2.x + u3.x);
        o.y = (u0.y + u1.y) + (u2.y + u3.y);
        o.z = (u0.z + u1.z) + (u2.z + u3.z);
        o.w = (u0.w + u1.w) + (u2.w + u3.w);
        reinterpret_cast<float4*>(ws_ps + (a * 8 + chunk) * 1024)[tid] = o;
    } else {
        // ---- patch_num: block (a2, chunk); wave wv = channel chunk*4+wv ----
        const int bb    = blk - 512;
        const int a2    = bb >> 3;     // bo*8 + h
        const int chunk = bb & 7;
        const int bo = a2 >> 3, h = a2 & 7;
        const int b  = bo * 32 + chunk * 4 + wv;
        const int i = lane >> 3, j = lane & 7;
        const float4* qv = reinterpret_cast<const float4*>(qpn) + ((b * 8 + i) * 8 + h) * 16;
        const float4* kv = reinterpret_cast<const float4*>(kpn) + ((b * 8 + j) * 8 + h) * 16;

        float acc = 0.f;
        #pragma unroll
        for (int c = 0; c < 16; ++c) {
            float4 q = qv[c], k = kv[c];
            acc = fmaf(q.x, k.x, acc);
            acc = fmaf(q.y, k.y, acc);
            acc = fmaf(q.z, k.z, acc);
            acc = fmaf(q.w, k.w, acc);
        }
        const float s = acc * 0.125f;
        float m = s;
        m = fmaxf(m, __shfl_xor(m, 1));
        m = fmaxf(m, __shfl_xor(m, 2));
        m = fmaxf(m, __shfl_xor(m, 4));
        float e = __expf(s - m);
        float sum = e;
        sum += __shfl_xor(sum, 1);
        sum += __shfl_xor(sum, 2);
        sum += __shfl_xor(sum, 4);

        red[wv][lane] = e / (sum * 32.f);
        __syncthreads();
        if (tid < 64) {
            ws_pn[(a2 * 8 + chunk) * 64 + tid] =
                (red[0][tid] + red[1][tid]) + (red[2][tid] + red[3][tid]);
        }
    }
}

// Collapse the 8 chunk-partials once: ws_ps[64][8][1024] -> ws0r[64][1024],
// ws_pn[64][8][64] -> ws1r[64][64]. 69,632 threads = 272 blocks.
__global__ __launch_bounds__(256)
void reduce_kernel(const float* __restrict__ ws_ps,
                   const float* __restrict__ ws_pn,
                   float* __restrict__ ws0r,
                   float* __restrict__ ws1r)
{
    const int g = blockIdx.x * 256 + threadIdx.x;
    if (g < 65536) {
        const int a = g >> 10, c = g & 1023;
        const float* base = ws_ps + a * 8192 + c;
        float v = 0.f;
        #pragma unroll
        for (int k = 0; k < 8; ++k) v += base[k * 1024];
        ws0r[g] = v;
    } else {
        const int h = g - 65536;           // < 4096
        const int a = h >> 6, c = h & 63;
        const float* base = ws_pn + a * 512 + c;
        float v = 0.f;
        #pragma unroll
        for (int k = 0; k < 8; ++k) v += base[k * 64];
        ws1r[h] = v;
    }
}

// Expansion writer: ONE L2-broadcast read + one float4 store per thread.
__global__ __launch_bounds__(256)
void writer_kernel(const float* __restrict__ ws0r,
                   const float* __restrict__ ws1r,
                   float* __restrict__ out)
{
    const int g = blockIdx.x * 256 + threadIdx.x;   // float4 index
    float4* o4 = reinterpret_cast<float4*>(out);
    if (g < 1048576) {
        // out0[a][i][j] = ws0r[a][(i>>3)*32 + (j>>3)]
        const int a  = g >> 14;
        const int r  = g & 16383;
        const int i  = r >> 6;
        const int j4 = r & 63;
        const float v = ws0r[a * 1024 + (i >> 3) * 32 + (j4 >> 1)];
        float4 o; o.x = v; o.y = v; o.z = v; o.w = v;
        o4[g] = o;
    } else {
        // out1[a][i][j] = ws1r[a][(i&7)*8 + (j&7)]
        const int g2 = g - 1048576;
        const int a  = g2 >> 14;
        const int r  = g2 & 16383;
        const int i  = r >> 6;
        const int j4 = r & 63;
        o4[g] = *reinterpret_cast<const float4*>(ws1r + a * 64 + (i & 7) * 8 + 4 * (j4 & 1));
    }
}

extern "C" void kernel_launch(void* const* d_in, const int* in_sizes, int n_in,
                              void* d_out, int out_size, void* d_ws, size_t ws_size,
                              hipStream_t stream) {
    // Size-scan input assignment (dict order: qps, kps, qpn, kpn)
    const float *qps = nullptr, *kps = nullptr, *qpn = nullptr, *kpn = nullptr;
    for (int idx = 0; idx < n_in; ++idx) {
        if (in_sizes[idx] == 256 * 32 * 8 * 64) {
            if (!qps) qps = (const float*)d_in[idx];
            else if (!kps) kps = (const float*)d_in[idx];
        } else if (in_sizes[idx] == 256 * 8 * 8 * 64) {
            if (!qpn) qpn = (const float*)d_in[idx];
            else if (!kpn) kpn = (const float*)d_in[idx];
        }
    }

    float* ws_ps = (float*)d_ws;            // 64*8*1024 floats (2 MB)
    float* ws_pn = ws_ps + 64 * 8 * 1024;   // 64*8*64 floats (128 KB)
    float* ws0r  = ws_pn + 64 * 8 * 64;     // 64*1024 floats (256 KB)
    float* ws1r  = ws0r + 64 * 1024;        // 64*64 floats (16 KB)

    scores_kernel<<<1024, 256, 0, stream>>>(qps, kps, qpn, kpn, ws_ps, ws_pn);
    reduce_kernel<<<272, 256, 0, stream>>>(ws_ps, ws_pn, ws0r, ws1r);
    writer_kernel<<<8192, 256, 0, stream>>>(ws0r, ws1r, (float*)d_out);
}

// Round 14
// 108.768 us; speedup vs baseline: 1.1021x; 1.1021x over previous
//
#include <hip/hip_runtime.h>
#include <stdint.h>

// fp32 inputs, fp32 outputs (established R8):
// qps/kps: [256][32][8][64] f32 ; qpn/kpn: [256][8][8][64] f32
// d_out: f32, FIRST s_ps repeat-expanded [8][8][256][256] (4,194,304 elems),
// THEN s_pn tiled [8][8][256][256].
// S[b,h,l,s] = (1/8)*sum_e Q[b,l,h,e]K[b,s,h,e]; softmax over s; mean over
// the 32 channels (b = bo*32+ch).
//
// R14: branch-A scores restructured for coalesced loads. R10-R13 showed the
// 8-way-replicated scattered loads (128 B unique/instr) are the bottleneck
// (~30 us vs 7 us BW floor; R11 more-scatter = 2x worse, R13 reg-dbuf =
// neutral). Now: 4 waves cooperatively stage one channel's Q+K tiles into
// LDS (double-buffered, 17-f4 pad) with coalesced 256B segments, compute
// from LDS (wave = 8 rows), accumulate 4-channel partial in registers,
// store coalesced. Channel loop pipelined: issue ch+1 loads -> compute ch
// -> ds_write ch+1 -> barrier. Branch B / reduce / writer = R12 verbatim.

__global__ __launch_bounds__(256, 4)
void scores_kernel(const float* __restrict__ qps,
                   const float* __restrict__ kps,
                   const float* __restrict__ qpn,
                   const float* __restrict__ kpn,
                   float* __restrict__ ws_ps,   // [64][8][1024] chunk partials
                   float* __restrict__ ws_pn)   // [64][8][64]   chunk partials
{
    // [buf][0]=Q tile, [buf][1]=K tile; 32 rows x 17 float4 (pad: +1 f4)
    __shared__ float4 tiles[2][2][32 * 17];    // 34,816 B
    const int tid  = threadIdx.x;
    const int wv   = tid >> 6;
    const int lane = tid & 63;
    const int blk  = blockIdx.x;

    if (blk < 512) {
        // ---- patch_size: block = (a, chunk); all 4 waves share one channel ----
        const int a     = blk >> 3;    // bo*8 + h
        const int chunk = blk & 7;
        const int bo = a >> 3, h = a & 7;
        const int b0 = bo * 32 + chunk * 4;     // first of 4 channels

        const float4* Q4 = reinterpret_cast<const float4*>(qps);
        const float4* K4 = reinterpret_cast<const float4*>(kps);

        // staging map: thread t covers (row = p*16 + (t>>4), f4 = t&15), p=0,1
        const int r0 = tid >> 4;       // 0..15
        const int f  = tid & 15;

        // compute map: wave wv owns rows wv*8..wv*8+7; lane = (row_in_8, j)
        const int myrow = wv * 8 + (lane >> 3);
        const int j     = lane & 7;    // cols 4j..4j+3

        float pa[4];
        #pragma unroll
        for (int u = 0; u < 4; ++u) pa[u] = 0.f;

        // prologue: stage channel 0 into buf 0
        float4 gq0, gq1, gk0, gk1;
        {
            const int b = b0;
            gq0 = Q4[((b * 32 + r0) * 8 + h) * 16 + f];
            gq1 = Q4[((b * 32 + 16 + r0) * 8 + h) * 16 + f];
            gk0 = K4[((b * 32 + r0) * 8 + h) * 16 + f];
            gk1 = K4[((b * 32 + 16 + r0) * 8 + h) * 16 + f];
            tiles[0][0][r0 * 17 + f]        = gq0;
            tiles[0][0][(16 + r0) * 17 + f] = gq1;
            tiles[0][1][r0 * 17 + f]        = gk0;
            tiles[0][1][(16 + r0) * 17 + f] = gk1;
        }
        __syncthreads();

        for (int ch = 0; ch < 4; ++ch) {
            const int buf = ch & 1;

            // issue next channel's global loads (latency hidden by compute)
            if (ch < 3) {
                const int b = b0 + ch + 1;
                gq0 = Q4[((b * 32 + r0) * 8 + h) * 16 + f];
                gq1 = Q4[((b * 32 + 16 + r0) * 8 + h) * 16 + f];
                gk0 = K4[((b * 32 + r0) * 8 + h) * 16 + f];
                gk1 = K4[((b * 32 + 16 + r0) * 8 + h) * 16 + f];
            }

            // compute: row myrow, cols 4j..4j+3, K=64 from LDS
            float acc[4];
            #pragma unroll
            for (int u = 0; u < 4; ++u) acc[u] = 0.f;
            #pragma unroll
            for (int c = 0; c < 16; ++c) {
                const float4 q = tiles[buf][0][myrow * 17 + c];
                #pragma unroll
                for (int u = 0; u < 4; ++u) {
                    const float4 k = tiles[buf][1][(4 * j + u) * 17 + c];
                    acc[u] = fmaf(q.x, k.x, acc[u]);
                    acc[u] = fmaf(q.y, k.y, acc[u]);
                    acc[u] = fmaf(q.z, k.z, acc[u]);
                    acc[u] = fmaf(q.w, k.w, acc[u]);
                }
            }

            // softmax over s (own 4 cols + shfl across j bits 1,2,4); /32 mean
            {
                float v0 = acc[0] * 0.125f, v1 = acc[1] * 0.125f;
                float v2 = acc[2] * 0.125f, v3 = acc[3] * 0.125f;
                float m = fmaxf(fmaxf(v0, v1), fmaxf(v2, v3));
                m = fmaxf(m, __shfl_xor(m, 1));
                m = fmaxf(m, __shfl_xor(m, 2));
                m = fmaxf(m, __shfl_xor(m, 4));
                float e0 = __expf(v0 - m), e1 = __expf(v1 - m);
                float e2 = __expf(v2 - m), e3 = __expf(v3 - m);
                float s = (e0 + e1) + (e2 + e3);
                s += __shfl_xor(s, 1);
                s += __shfl_xor(s, 2);
                s += __shfl_xor(s, 4);
                const float inv = 1.f / (s * 32.f);
                pa[0] += e0 * inv; pa[1] += e1 * inv;
                pa[2] += e2 * inv; pa[3] += e3 * inv;
            }

            // write next channel into the other buffer, then barrier
            if (ch < 3) {
                const int nb = buf ^ 1;
                tiles[nb][0][r0 * 17 + f]        = gq0;
                tiles[nb][0][(16 + r0) * 17 + f] = gq1;
                tiles[nb][1][r0 * 17 + f]        = gk0;
                tiles[nb][1][(16 + r0) * 17 + f] = gk1;
            }
            __syncthreads();
        }

        // coalesced store of the 4-channel partial: f4 index = row*8 + j
        float4 o; o.x = pa[0]; o.y = pa[1]; o.z = pa[2]; o.w = pa[3];
        reinterpret_cast<float4*>(ws_ps + (a * 8 + chunk) * 1024)[myrow * 8 + j] = o;
    } else {
        // ---- patch_num: block (a2, chunk); wave wv = channel chunk*4+wv ----
        float* red = reinterpret_cast<float*>(tiles);   // [4][64] reuse
        const int bb    = blk - 512;
        const int a2    = bb >> 3;     // bo*8 + h
        const int chunk = bb & 7;
        const int bo = a2 >> 3, h = a2 & 7;
        const int b  = bo * 32 + chunk * 4 + wv;
        const int i = lane >> 3, j = lane & 7;
        const float4* qv = reinterpret_cast<const float4*>(qpn) + ((b * 8 + i) * 8 + h) * 16;
        const float4* kv = reinterpret_cast<const float4*>(kpn) + ((b * 8 + j) * 8 + h) * 16;

        float acc = 0.f;
        #pragma unroll
        for (int c = 0; c < 16; ++c) {
            float4 q = qv[c], k = kv[c];
            acc = fmaf(q.x, k.x, acc);
            acc = fmaf(q.y, k.y, acc);
            acc = fmaf(q.z, k.z, acc);
            acc = fmaf(q.w, k.w, acc);
        }
        const float s = acc * 0.125f;
        float m = s;
        m = fmaxf(m, __shfl_xor(m, 1));
        m = fmaxf(m, __shfl_xor(m, 2));
        m = fmaxf(m, __shfl_xor(m, 4));
        float e = __expf(s - m);
        float sum = e;
        sum += __shfl_xor(sum, 1);
        sum += __shfl_xor(sum, 2);
        sum += __shfl_xor(sum, 4);

        red[wv * 64 + lane] = e / (sum * 32.f);
        __syncthreads();
        if (tid < 64) {
            ws_pn[(a2 * 8 + chunk) * 64 + tid] =
                (red[0 * 64 + tid] + red[1 * 64 + tid]) +
                (red[2 * 64 + tid] + red[3 * 64 + tid]);
        }
    }
}

// Collapse the 8 chunk-partials once: ws_ps[64][8][1024] -> ws0r[64][1024],
// ws_pn[64][8][64] -> ws1r[64][64]. 69,632 threads = 272 blocks.
__global__ __launch_bounds__(256)
void reduce_kernel(const float* __restrict__ ws_ps,
                   const float* __restrict__ ws_pn,
                   float* __restrict__ ws0r,
                   float* __restrict__ ws1r)
{
    const int g = blockIdx.x * 256 + threadIdx.x;
    if (g < 65536) {
        const int a = g >> 10, c = g & 1023;
        const float* base = ws_ps + a * 8192 + c;
        float v = 0.f;
        #pragma unroll
        for (int k = 0; k < 8; ++k) v += base[k * 1024];
        ws0r[g] = v;
    } else {
        const int h = g - 65536;           // < 4096
        const int a = h >> 6, c = h & 63;
        const float* base = ws_pn + a * 512 + c;
        float v = 0.f;
        #pragma unroll
        for (int k = 0; k < 8; ++k) v += base[k * 64];
        ws1r[h] = v;
    }
}

// Expansion writer: ONE L2-broadcast read + one float4 store per thread.
__global__ __launch_bounds__(256)
void writer_kernel(const float* __restrict__ ws0r,
                   const float* __restrict__ ws1r,
                   float* __restrict__ out)
{
    const int g = blockIdx.x * 256 + threadIdx.x;   // float4 index
    float4* o4 = reinterpret_cast<float4*>(out);
    if (g < 1048576) {
        // out0[a][i][j] = ws0r[a][(i>>3)*32 + (j>>3)]
        const int a  = g >> 14;
        const int r  = g & 16383;
        const int i  = r >> 6;
        const int j4 = r & 63;
        const float v = ws0r[a * 1024 + (i >> 3) * 32 + (j4 >> 1)];
        float4 o; o.x = v; o.y = v; o.z = v; o.w = v;
        o4[g] = o;
    } else {
        // out1[a][i][j] = ws1r[a][(i&7)*8 + (j&7)]
        const int g2 = g - 1048576;
        const int a  = g2 >> 14;
        const int r  = g2 & 16383;
        const int i  = r >> 6;
        const int j4 = r & 63;
        o4[g] = *reinterpret_cast<const float4*>(ws1r + a * 64 + (i & 7) * 8 + 4 * (j4 & 1));
    }
}

extern "C" void kernel_launch(void* const* d_in, const int* in_sizes, int n_in,
                              void* d_out, int out_size, void* d_ws, size_t ws_size,
                              hipStream_t stream) {
    // Size-scan input assignment (dict order: qps, kps, qpn, kpn)
    const float *qps = nullptr, *kps = nullptr, *qpn = nullptr, *kpn = nullptr;
    for (int idx = 0; idx < n_in; ++idx) {
        if (in_sizes[idx] == 256 * 32 * 8 * 64) {
            if (!qps) qps = (const float*)d_in[idx];
            else if (!kps) kps = (const float*)d_in[idx];
        } else if (in_sizes[idx] == 256 * 8 * 8 * 64) {
            if (!qpn) qpn = (const float*)d_in[idx];
            else if (!kpn) kpn = (const float*)d_in[idx];
        }
    }

    float* ws_ps = (float*)d_ws;            // 64*8*1024 floats (2 MB)
    float* ws_pn = ws_ps + 64 * 8 * 1024;   // 64*8*64 floats (128 KB)
    float* ws0r  = ws_pn + 64 * 8 * 64;     // 64*1024 floats (256 KB)
    float* ws1r  = ws0r + 64 * 1024;        // 64*64 floats (16 KB)

    scores_kernel<<<1024, 256, 0, stream>>>(qps, kps, qpn, kpn, ws_ps, ws_pn);
    reduce_kernel<<<272, 256, 0, stream>>>(ws_ps, ws_pn, ws0r, ws1r);
    writer_kernel<<<8192, 256, 0, stream>>>(ws0r, ws1r, (float*)d_out);
}